// Round 1
// baseline (1203.397 us; speedup 1.0000x reference)
//
#include <hip/hip_runtime.h>

#define NN 50000
#define CC 128

// ---------------- Kernel 1: xw = x @ W  (fp32, vector ALU) ----------------
// block = 256 threads = 8 rows x 32 lanes x float4; x rows staged in LDS.
__global__ void xw_kernel(const float* __restrict__ x, const float* __restrict__ w,
                          float* __restrict__ xw, int n) {
    __shared__ float xs[8][CC];
    const int tid = threadIdx.x;
    const int block_row = blockIdx.x * 8;
    for (int i = tid; i < 8 * CC; i += 256) {
        int r = block_row + (i >> 7);
        xs[i >> 7][i & 127] = (r < n) ? x[r * CC + (i & 127)] : 0.0f;
    }
    __syncthreads();
    const int lr = tid >> 5;          // local row 0..7
    const int lc = (tid & 31) * 4;    // col group
    float4 acc = make_float4(0.f, 0.f, 0.f, 0.f);
    #pragma unroll 4
    for (int k = 0; k < CC; ++k) {
        const float xv = xs[lr][k];
        const float4 wv = *reinterpret_cast<const float4*>(&w[k * CC + lc]);
        acc.x += xv * wv.x; acc.y += xv * wv.y;
        acc.z += xv * wv.z; acc.w += xv * wv.w;
    }
    const int r = block_row + lr;
    if (r < n) *reinterpret_cast<float4*>(&xw[r * CC + lc]) = acc;
}

// ---------------- Kernel 2: degree histogram over rows ----------------
__global__ void deg_kernel(const int* __restrict__ row, float* __restrict__ deg, int E) {
    int i = blockIdx.x * blockDim.x + threadIdx.x;
    int stride = gridDim.x * blockDim.x;
    for (; i < E; i += stride) {
        atomicAdd(&deg[row[i]], 1.0f);
    }
}

// ---------------- Kernel 3: dinv = deg>0 ? rsqrt(deg) : 0 ----------------
__global__ void dinv_kernel(const float* __restrict__ deg, float* __restrict__ dinv, int n) {
    int i = blockIdx.x * blockDim.x + threadIdx.x;
    if (i < n) {
        float d = deg[i];
        dinv[i] = (d > 0.0f) ? rsqrtf(d) : 0.0f;
    }
}

// ---------------- Kernel 4: message + scatter-add ----------------
// 32 lanes per edge, float4 per lane (128 floats per edge).
__global__ void scatter_kernel(const float* __restrict__ xw,
                               const int* __restrict__ ei,       // [2, E]
                               const int* __restrict__ ef,       // [E, 3]
                               const float* __restrict__ emb0,
                               const float* __restrict__ emb1,
                               const float* __restrict__ emb2,
                               const float* __restrict__ dinv,
                               float* __restrict__ out, int E) {
    const int e = blockIdx.x * 8 + (threadIdx.x >> 5);
    if (e >= E) return;
    const int lane = threadIdx.x & 31;

    const int row = ei[e];
    const int col = ei[E + e];
    const int f0 = ef[e * 3 + 0];
    const int f1 = ef[e * 3 + 1];
    const int f2 = ef[e * 3 + 2];
    const float norm = dinv[row] * dinv[col];

    const float4 a  = *reinterpret_cast<const float4*>(&xw[row * CC + lane * 4]);
    const float4 b0 = *reinterpret_cast<const float4*>(&emb0[f0 * CC + lane * 4]);
    const float4 b1 = *reinterpret_cast<const float4*>(&emb1[f1 * CC + lane * 4]);
    const float4 b2 = *reinterpret_cast<const float4*>(&emb2[f2 * CC + lane * 4]);

    const float vx = norm * (a.x + b0.x + b1.x + b2.x);
    const float vy = norm * (a.y + b0.y + b1.y + b2.y);
    const float vz = norm * (a.z + b0.z + b1.z + b2.z);
    const float vw = norm * (a.w + b0.w + b1.w + b2.w);

    float* o = &out[(size_t)col * CC + lane * 4];
    atomicAdd(o + 0, vx);
    atomicAdd(o + 1, vy);
    atomicAdd(o + 2, vz);
    atomicAdd(o + 3, vw);
}

extern "C" void kernel_launch(void* const* d_in, const int* in_sizes, int n_in,
                              void* d_out, int out_size, void* d_ws, size_t ws_size,
                              hipStream_t stream) {
    const float* x      = (const float*)d_in[0];
    const int*   ei     = (const int*)d_in[1];
    const int*   ef     = (const int*)d_in[2];
    const float* weight = (const float*)d_in[3];
    const float* emb0   = (const float*)d_in[4];
    const float* emb1   = (const float*)d_in[5];
    const float* emb2   = (const float*)d_in[6];
    float* out = (float*)d_out;

    const int n = in_sizes[0] / CC;        // 50000
    const int E = in_sizes[1] / 2;         // 625000

    // workspace layout: xw [n*CC] | deg [n] | dinv [n]
    float* xw   = (float*)d_ws;
    float* deg  = xw + (size_t)n * CC;
    float* dinv = deg + n;

    // zero the accumulation targets
    hipMemsetAsync(out, 0, (size_t)out_size * sizeof(float), stream);
    hipMemsetAsync(deg, 0, (size_t)n * sizeof(float), stream);

    // 1) xw = x @ W
    xw_kernel<<<(n + 7) / 8, 256, 0, stream>>>(x, weight, xw, n);

    // 2) degree
    deg_kernel<<<2048, 256, 0, stream>>>(ei, deg, E);

    // 3) dinv
    dinv_kernel<<<(n + 255) / 256, 256, 0, stream>>>(deg, dinv, n);

    // 4) message + scatter
    scatter_kernel<<<(E + 7) / 8, 256, 0, stream>>>(xw, ei, ef, emb0, emb1, emb2,
                                                    dinv, out, E);
}

// Round 2
// 363.081 us; speedup vs baseline: 3.3144x; 3.3144x over previous
//
#include <hip/hip_runtime.h>

#define CC 128

// ---------------- Kernel 1: xw = x @ W  (fp32, vector ALU) ----------------
__global__ void xw_kernel(const float* __restrict__ x, const float* __restrict__ w,
                          float* __restrict__ xw, int n) {
    __shared__ float xs[8][CC];
    const int tid = threadIdx.x;
    const int block_row = blockIdx.x * 8;
    for (int i = tid; i < 8 * CC; i += 256) {
        int r = block_row + (i >> 7);
        xs[i >> 7][i & 127] = (r < n) ? x[r * CC + (i & 127)] : 0.0f;
    }
    __syncthreads();
    const int lr = tid >> 5;          // local row 0..7
    const int lc = (tid & 31) * 4;    // col group
    float4 acc = make_float4(0.f, 0.f, 0.f, 0.f);
    #pragma unroll 4
    for (int k = 0; k < CC; ++k) {
        const float xv = xs[lr][k];
        const float4 wv = *reinterpret_cast<const float4*>(&w[k * CC + lc]);
        acc.x += xv * wv.x; acc.y += xv * wv.y;
        acc.z += xv * wv.z; acc.w += xv * wv.w;
    }
    const int r = block_row + lr;
    if (r < n) *reinterpret_cast<float4*>(&xw[r * CC + lc]) = acc;
}

// ---------------- Kernel 2: row & col histograms (int atomics) ----------------
__global__ void hist_kernel(const int* __restrict__ ei, int* __restrict__ cnt_row,
                            int* __restrict__ cnt_col, int E) {
    int i = blockIdx.x * blockDim.x + threadIdx.x;
    int stride = gridDim.x * blockDim.x;
    for (; i < E; i += stride) {
        atomicAdd(&cnt_row[ei[i]], 1);
        atomicAdd(&cnt_col[ei[E + i]], 1);
    }
}

// ---------------- Kernel 3: dinv = rsqrt(deg_row) ----------------
__global__ void dinv_kernel(const int* __restrict__ cnt_row, float* __restrict__ dinv, int n) {
    int i = blockIdx.x * blockDim.x + threadIdx.x;
    if (i < n) {
        int d = cnt_row[i];
        dinv[i] = (d > 0) ? rsqrtf((float)d) : 0.0f;
    }
}

// ---------------- Kernel 4: single-block exclusive scan of cnt_col ----------------
__global__ void scan_kernel(const int* __restrict__ cnt, int* __restrict__ offs,
                            int* __restrict__ next, int n) {
    __shared__ int tmp[1024];
    __shared__ int srun;
    const int tid = threadIdx.x;
    if (tid == 0) srun = 0;
    __syncthreads();
    for (int base = 0; base < n; base += 1024) {
        int i = base + tid;
        int v = (i < n) ? cnt[i] : 0;
        tmp[tid] = v;
        __syncthreads();
        #pragma unroll
        for (int d = 1; d < 1024; d <<= 1) {
            int t = (tid >= d) ? tmp[tid - d] : 0;
            __syncthreads();
            tmp[tid] += t;
            __syncthreads();
        }
        int incl = tmp[tid];          // inclusive scan of this chunk
        int excl = incl - v;
        int run = srun;
        if (i < n) {
            offs[i] = run + excl;
            next[i] = run + excl;
        }
        __syncthreads();
        if (tid == 1023) srun = run + incl;   // chunk total
        __syncthreads();
    }
    if (tid == 0) offs[n] = srun;
}

// ---------------- Kernel 5: fill CSR (sorted-by-col edge records) ----------------
__global__ void fill_kernel(const int* __restrict__ ei, const int* __restrict__ ef,
                            int* __restrict__ next, int2* __restrict__ sc, int E) {
    int i = blockIdx.x * blockDim.x + threadIdx.x;
    int stride = gridDim.x * blockDim.x;
    for (; i < E; i += stride) {
        int r = ei[i];
        int c = ei[E + i];
        int pos = atomicAdd(&next[c], 1);
        int f0 = ef[i * 3 + 0], f1 = ef[i * 3 + 1], f2 = ef[i * 3 + 2];
        sc[pos] = make_int2(r, f0 * 12 + f1 * 2 + f2);
    }
}

// ---------------- Kernel 6: combo embedding table [60][CC] ----------------
__global__ void combo_kernel(const float* __restrict__ emb0, const float* __restrict__ emb1,
                             const float* __restrict__ emb2, float* __restrict__ combo) {
    int c = blockIdx.x;           // 0..59
    int t = threadIdx.x;          // 0..127
    int i = c / 12;
    int j = (c % 12) / 2;
    int k = c % 2;
    combo[c * CC + t] = emb0[i * CC + t] + emb1[j * CC + t] + emb2[k * CC + t];
}

// ---------------- Kernel 7: gather (one 64-lane wave per node) ----------------
__global__ void gather_kernel(const float* __restrict__ xw, const int2* __restrict__ sc,
                              const int* __restrict__ offs, const float* __restrict__ dinv,
                              const float* __restrict__ combo, float* __restrict__ out, int n) {
    const int v = blockIdx.x * 4 + (threadIdx.x >> 6);
    if (v >= n) return;
    const int lane = threadIdx.x & 63;
    const int beg = offs[v];
    const int end = offs[v + 1];
    float2 acc = make_float2(0.f, 0.f);
    for (int j = beg; j < end; ++j) {
        const int2 e = sc[j];
        const float w = dinv[e.x];
        const float2 xv = *reinterpret_cast<const float2*>(&xw[(size_t)e.x * CC + lane * 2]);
        const float2 cv = *reinterpret_cast<const float2*>(&combo[e.y * CC + lane * 2]);
        acc.x += w * (xv.x + cv.x);
        acc.y += w * (xv.y + cv.y);
    }
    const float s = dinv[v];
    *reinterpret_cast<float2*>(&out[(size_t)v * CC + lane * 2]) =
        make_float2(s * acc.x, s * acc.y);
}

extern "C" void kernel_launch(void* const* d_in, const int* in_sizes, int n_in,
                              void* d_out, int out_size, void* d_ws, size_t ws_size,
                              hipStream_t stream) {
    const float* x      = (const float*)d_in[0];
    const int*   ei     = (const int*)d_in[1];
    const int*   ef     = (const int*)d_in[2];
    const float* weight = (const float*)d_in[3];
    const float* emb0   = (const float*)d_in[4];
    const float* emb1   = (const float*)d_in[5];
    const float* emb2   = (const float*)d_in[6];
    float* out = (float*)d_out;

    const int n = in_sizes[0] / CC;        // 50000
    const int E = in_sizes[1] / 2;         // 625000

    // ---- workspace layout (16B-aligned chunks) ----
    char* p = (char*)d_ws;
    auto alloc = [&](size_t bytes) {
        char* r = p;
        p += (bytes + 15) & ~(size_t)15;
        return r;
    };
    float* xw      = (float*)alloc((size_t)n * CC * sizeof(float));
    float* combo   = (float*)alloc(60 * CC * sizeof(float));
    float* dinv    = (float*)alloc(n * sizeof(float));
    int*   cnt_row = (int*)alloc(n * sizeof(int));
    int*   cnt_col = (int*)alloc(n * sizeof(int));
    int*   offs    = (int*)alloc((n + 1) * sizeof(int));
    int*   next    = (int*)alloc(n * sizeof(int));
    int2*  sc      = (int2*)alloc((size_t)E * sizeof(int2));

    hipMemsetAsync(cnt_row, 0, n * sizeof(int), stream);
    hipMemsetAsync(cnt_col, 0, n * sizeof(int), stream);

    // 1) xw = x @ W
    xw_kernel<<<(n + 7) / 8, 256, 0, stream>>>(x, weight, xw, n);
    // 2) histograms
    hist_kernel<<<2048, 256, 0, stream>>>(ei, cnt_row, cnt_col, E);
    // 3) dinv
    dinv_kernel<<<(n + 255) / 256, 256, 0, stream>>>(cnt_row, dinv, n);
    // 4) scan cnt_col -> offs, next
    scan_kernel<<<1, 1024, 0, stream>>>(cnt_col, offs, next, n);
    // 5) fill CSR records
    fill_kernel<<<2048, 256, 0, stream>>>(ei, ef, next, sc, E);
    // 6) combo table
    combo_kernel<<<60, CC, 0, stream>>>(emb0, emb1, emb2, combo);
    // 7) gather
    gather_kernel<<<(n + 3) / 4, 256, 0, stream>>>(xw, sc, offs, dinv, combo, out, n);
}

// Round 3
// 207.424 us; speedup vs baseline: 5.8016x; 1.7504x over previous
//
#include <hip/hip_runtime.h>

#define CC 128

// ---------------- Kernel 1: xw = x @ W  (fp32, W in LDS, 4x16 reg tile) ----
// block = 256 threads (4 waves), 128 rows x 128 cols per block.
// wave (wr,wc) covers rows wr*64.. , cols wc*64.. ; lane = 16 row-groups x 4 col-groups.
__global__ __launch_bounds__(256) void xw_kernel(const float* __restrict__ x,
                                                 const float* __restrict__ w,
                                                 float* __restrict__ xw, int n) {
    __shared__ float ws[CC * CC];            // 64 KB
    const int tid = threadIdx.x;
    // stage W (coalesced float4)
    for (int i = tid * 4; i < CC * CC; i += 256 * 4)
        *reinterpret_cast<float4*>(&ws[i]) = *reinterpret_cast<const float4*>(&w[i]);
    __syncthreads();

    const int wave = tid >> 6;
    const int lane = tid & 63;
    const int wr = wave >> 1, wc = wave & 1;
    const int lr = lane >> 2, lc = lane & 3;
    const int row0 = blockIdx.x * 128 + wr * 64 + lr * 4;   // 4 rows
    const int col0 = wc * 64 + lc * 16;                     // 16 cols

    float acc[4][16] = {};
    for (int k = 0; k < CC; k += 4) {
        float4 xv[4];
        #pragma unroll
        for (int r = 0; r < 4; ++r)
            xv[r] = (row0 + r < n)
                  ? *reinterpret_cast<const float4*>(&x[(size_t)(row0 + r) * CC + k])
                  : make_float4(0.f, 0.f, 0.f, 0.f);
        #pragma unroll
        for (int kk = 0; kk < 4; ++kk) {
            float wv[16];
            #pragma unroll
            for (int c4 = 0; c4 < 4; ++c4)
                *reinterpret_cast<float4*>(&wv[c4 * 4]) =
                    *reinterpret_cast<float4*>(&ws[(k + kk) * CC + col0 + c4 * 4]);
            #pragma unroll
            for (int r = 0; r < 4; ++r) {
                const float xs = (&xv[r].x)[kk];
                #pragma unroll
                for (int c = 0; c < 16; ++c)
                    acc[r][c] += xs * wv[c];
            }
        }
    }
    #pragma unroll
    for (int r = 0; r < 4; ++r) {
        if (row0 + r < n) {
            #pragma unroll
            for (int c4 = 0; c4 < 4; ++c4)
                *reinterpret_cast<float4*>(&xw[(size_t)(row0 + r) * CC + col0 + c4 * 4]) =
                    *reinterpret_cast<float4*>(&acc[r][c4 * 4]);
        }
    }
}

// ---------------- Kernel 2: row & col histograms (int atomics) ----------------
__global__ void hist_kernel(const int* __restrict__ ei, int* __restrict__ cnt_row,
                            int* __restrict__ cnt_col, int E) {
    int i = blockIdx.x * blockDim.x + threadIdx.x;
    int stride = gridDim.x * blockDim.x;
    for (; i < E; i += stride) {
        atomicAdd(&cnt_row[ei[i]], 1);
        atomicAdd(&cnt_col[ei[E + i]], 1);
    }
}

// ---------------- Kernel 3: dinv = rsqrt(deg_row) ----------------
__global__ void dinv_kernel(const int* __restrict__ cnt_row, float* __restrict__ dinv, int n) {
    int i = blockIdx.x * blockDim.x + threadIdx.x;
    if (i < n) {
        int d = cnt_row[i];
        dinv[i] = (d > 0) ? rsqrtf((float)d) : 0.0f;
    }
}

// ---------------- Kernels 4a/4b/4c: 3-phase exclusive scan of cnt_col -------
__global__ void blocksum_kernel(const int* __restrict__ cnt, int* __restrict__ bsum, int n) {
    int i = blockIdx.x * 256 + threadIdx.x;
    int v = (i < n) ? cnt[i] : 0;
    #pragma unroll
    for (int d = 32; d; d >>= 1) v += __shfl_down(v, d);
    __shared__ int wsum[4];
    if ((threadIdx.x & 63) == 0) wsum[threadIdx.x >> 6] = v;
    __syncthreads();
    if (threadIdx.x == 0) bsum[blockIdx.x] = wsum[0] + wsum[1] + wsum[2] + wsum[3];
}

__global__ void bscan_kernel(const int* __restrict__ bsum, int* __restrict__ boff,
                             int nb, int* __restrict__ offs, int n) {
    __shared__ int tmp[256];
    const int t = threadIdx.x;
    int v = (t < nb) ? bsum[t] : 0;
    tmp[t] = v; __syncthreads();
    for (int d = 1; d < 256; d <<= 1) {
        int u = (t >= d) ? tmp[t - d] : 0; __syncthreads();
        tmp[t] += u; __syncthreads();
    }
    if (t < nb) boff[t] = tmp[t] - v;
    if (t == 255) offs[n] = tmp[255];     // total = E
}

__global__ void offs_kernel(const int* __restrict__ cnt, const int* __restrict__ boff,
                            int* __restrict__ offs, int* __restrict__ next, int n) {
    __shared__ int tmp[256];
    const int t = threadIdx.x;
    const int i = blockIdx.x * 256 + t;
    int v = (i < n) ? cnt[i] : 0;
    tmp[t] = v; __syncthreads();
    for (int d = 1; d < 256; d <<= 1) {
        int u = (t >= d) ? tmp[t - d] : 0; __syncthreads();
        tmp[t] += u; __syncthreads();
    }
    if (i < n) {
        int e = boff[blockIdx.x] + tmp[t] - v;
        offs[i] = e;
        next[i] = e;
    }
}

// ---------------- Kernel 5: fill CSR records (row|code packed, dinv_row) ----
// NOTE: relies on n <= 65536 so row fits in 16 bits (n = 50000 here).
__global__ void fill_kernel(const int* __restrict__ ei, const int* __restrict__ ef,
                            const float* __restrict__ dinv, int* __restrict__ next,
                            int2* __restrict__ sc, int E) {
    int i = blockIdx.x * blockDim.x + threadIdx.x;
    int stride = gridDim.x * blockDim.x;
    for (; i < E; i += stride) {
        int r = ei[i];
        int c = ei[E + i];
        int pos = atomicAdd(&next[c], 1);
        int code = ef[i * 3 + 0] * 12 + ef[i * 3 + 1] * 2 + ef[i * 3 + 2];
        sc[pos] = make_int2(r | (code << 16), __float_as_int(dinv[r]));
    }
}

// ---------------- Kernel 6: combo embedding table [60][CC] ----------------
__global__ void combo_kernel(const float* __restrict__ emb0, const float* __restrict__ emb1,
                             const float* __restrict__ emb2, float* __restrict__ combo) {
    int c = blockIdx.x;           // 0..59
    int t = threadIdx.x;          // 0..127
    int i = c / 12;
    int j = (c % 12) / 2;
    int k = c % 2;
    combo[c * CC + t] = emb0[i * CC + t] + emb1[j * CC + t] + emb2[k * CC + t];
}

// ---------------- Kernel 7: gather (one 64-lane wave per node, unroll 2) ----
__global__ void gather_kernel(const float* __restrict__ xw, const int2* __restrict__ sc,
                              const int* __restrict__ offs, const float* __restrict__ dinv,
                              const float* __restrict__ combo, float* __restrict__ out, int n) {
    const int v = blockIdx.x * 4 + (threadIdx.x >> 6);
    if (v >= n) return;
    const int lane = threadIdx.x & 63;
    int j = offs[v];
    const int end = offs[v + 1];
    float2 a0 = make_float2(0.f, 0.f), a1 = make_float2(0.f, 0.f);
    for (; j + 2 <= end; j += 2) {
        const int2 e0 = sc[j];
        const int2 e1 = sc[j + 1];
        const int   r0 = e0.x & 0xFFFF, c0 = e0.x >> 16;
        const int   r1 = e1.x & 0xFFFF, c1 = e1.x >> 16;
        const float w0 = __int_as_float(e0.y);
        const float w1 = __int_as_float(e1.y);
        const float2 x0 = *reinterpret_cast<const float2*>(&xw[(size_t)r0 * CC + lane * 2]);
        const float2 k0 = *reinterpret_cast<const float2*>(&combo[c0 * CC + lane * 2]);
        const float2 x1 = *reinterpret_cast<const float2*>(&xw[(size_t)r1 * CC + lane * 2]);
        const float2 k1 = *reinterpret_cast<const float2*>(&combo[c1 * CC + lane * 2]);
        a0.x += w0 * (x0.x + k0.x); a0.y += w0 * (x0.y + k0.y);
        a1.x += w1 * (x1.x + k1.x); a1.y += w1 * (x1.y + k1.y);
    }
    if (j < end) {
        const int2 e0 = sc[j];
        const int   r0 = e0.x & 0xFFFF, c0 = e0.x >> 16;
        const float w0 = __int_as_float(e0.y);
        const float2 x0 = *reinterpret_cast<const float2*>(&xw[(size_t)r0 * CC + lane * 2]);
        const float2 k0 = *reinterpret_cast<const float2*>(&combo[c0 * CC + lane * 2]);
        a0.x += w0 * (x0.x + k0.x); a0.y += w0 * (x0.y + k0.y);
    }
    const float s = dinv[v];
    *reinterpret_cast<float2*>(&out[(size_t)v * CC + lane * 2]) =
        make_float2(s * (a0.x + a1.x), s * (a0.y + a1.y));
}

extern "C" void kernel_launch(void* const* d_in, const int* in_sizes, int n_in,
                              void* d_out, int out_size, void* d_ws, size_t ws_size,
                              hipStream_t stream) {
    const float* x      = (const float*)d_in[0];
    const int*   ei     = (const int*)d_in[1];
    const int*   ef     = (const int*)d_in[2];
    const float* weight = (const float*)d_in[3];
    const float* emb0   = (const float*)d_in[4];
    const float* emb1   = (const float*)d_in[5];
    const float* emb2   = (const float*)d_in[6];
    float* out = (float*)d_out;

    const int n = in_sizes[0] / CC;        // 50000
    const int E = in_sizes[1] / 2;         // 625000
    const int nb = (n + 255) / 256;        // scan blocks (196)

    // ---- workspace layout (16B-aligned chunks) ----
    char* p = (char*)d_ws;
    auto alloc = [&](size_t bytes) {
        char* r = p;
        p += (bytes + 15) & ~(size_t)15;
        return r;
    };
    float* xw      = (float*)alloc((size_t)n * CC * sizeof(float));
    float* combo   = (float*)alloc(60 * CC * sizeof(float));
    float* dinv    = (float*)alloc(n * sizeof(float));
    int*   cnt_row = (int*)alloc(n * sizeof(int));
    int*   cnt_col = (int*)alloc(n * sizeof(int));
    int*   offs    = (int*)alloc((n + 1) * sizeof(int));
    int*   next    = (int*)alloc(n * sizeof(int));
    int*   bsum    = (int*)alloc(nb * sizeof(int));
    int*   boff    = (int*)alloc(nb * sizeof(int));
    int2*  sc      = (int2*)alloc((size_t)E * sizeof(int2));

    hipMemsetAsync(cnt_row, 0, n * sizeof(int), stream);
    hipMemsetAsync(cnt_col, 0, n * sizeof(int), stream);

    // 1) xw = x @ W
    xw_kernel<<<(n + 127) / 128, 256, 0, stream>>>(x, weight, xw, n);
    // 2) histograms
    hist_kernel<<<2048, 256, 0, stream>>>(ei, cnt_row, cnt_col, E);
    // 3) dinv
    dinv_kernel<<<(n + 255) / 256, 256, 0, stream>>>(cnt_row, dinv, n);
    // 4) scan cnt_col -> offs, next
    blocksum_kernel<<<nb, 256, 0, stream>>>(cnt_col, bsum, n);
    bscan_kernel<<<1, 256, 0, stream>>>(bsum, boff, nb, offs, n);
    offs_kernel<<<nb, 256, 0, stream>>>(cnt_col, boff, offs, next, n);
    // 5) fill CSR records
    fill_kernel<<<2048, 256, 0, stream>>>(ei, ef, dinv, next, sc, E);
    // 6) combo table
    combo_kernel<<<60, CC, 0, stream>>>(emb0, emb1, emb2, combo);
    // 7) gather
    gather_kernel<<<(n + 3) / 4, 256, 0, stream>>>(xw, sc, offs, dinv, combo, out, n);
}

// Round 4
// 190.223 us; speedup vs baseline: 6.3263x; 1.0904x over previous
//
#include <hip/hip_runtime.h>

#define CC 128
typedef unsigned short ushort_t;
typedef unsigned int uint_t;

__device__ __forceinline__ ushort_t f2bf(float f) {
    uint_t u = __float_as_uint(f);
    u = (u + 0x7FFFu + ((u >> 16) & 1u)) >> 16;   // RNE
    return (ushort_t)u;
}

// ---------------- Kernel 1: xw = x @ W  (fp32 math, bf16 store) ------------
// block = 256 threads, 128 rows x 128 cols; W staged in 16KB K-chunks.
__global__ __launch_bounds__(256) void xw_kernel(const float* __restrict__ x,
                                                 const float* __restrict__ w,
                                                 ushort_t* __restrict__ xwb, int n) {
    __shared__ float ws[32 * CC];            // 16 KB
    const int tid = threadIdx.x;
    const int wave = tid >> 6;
    const int lane = tid & 63;
    const int wr = wave >> 1, wc = wave & 1;
    const int lr = lane >> 2, lc = lane & 3;
    const int row0 = blockIdx.x * 128 + wr * 64 + lr * 4;   // 4 rows
    const int col0 = wc * 64 + lc * 16;                     // 16 cols

    float acc[4][16] = {};
    for (int c = 0; c < 4; ++c) {
        const int k0 = c * 32;
        // stage W[k0..k0+32) rows (16 KB), coalesced float4
        {
            const float4* src = reinterpret_cast<const float4*>(&w[k0 * CC]);
            float4* dst = reinterpret_cast<float4*>(ws);
            #pragma unroll
            for (int i = 0; i < 4; ++i) dst[tid + i * 256] = src[tid + i * 256];
        }
        __syncthreads();
        for (int k = 0; k < 32; k += 4) {
            float4 xv[4];
            #pragma unroll
            for (int r = 0; r < 4; ++r)
                xv[r] = (row0 + r < n)
                      ? *reinterpret_cast<const float4*>(&x[(size_t)(row0 + r) * CC + k0 + k])
                      : make_float4(0.f, 0.f, 0.f, 0.f);
            #pragma unroll
            for (int kk = 0; kk < 4; ++kk) {
                float wv[16];
                #pragma unroll
                for (int c4 = 0; c4 < 4; ++c4)
                    *reinterpret_cast<float4*>(&wv[c4 * 4]) =
                        *reinterpret_cast<float4*>(&ws[(k + kk) * CC + col0 + c4 * 4]);
                #pragma unroll
                for (int r = 0; r < 4; ++r) {
                    const float xs = (&xv[r].x)[kk];
                    #pragma unroll
                    for (int cc = 0; cc < 16; ++cc)
                        acc[r][cc] += xs * wv[cc];
                }
            }
        }
        __syncthreads();
    }
    #pragma unroll
    for (int r = 0; r < 4; ++r) {
        if (row0 + r < n) {
            uint_t pk[8];
            #pragma unroll
            for (int c2 = 0; c2 < 8; ++c2)
                pk[c2] = (uint_t)f2bf(acc[r][c2 * 2]) | ((uint_t)f2bf(acc[r][c2 * 2 + 1]) << 16);
            ushort_t* o = &xwb[(size_t)(row0 + r) * CC + col0];
            *reinterpret_cast<uint4*>(o)     = *reinterpret_cast<uint4*>(pk);
            *reinterpret_cast<uint4*>(o + 8) = *reinterpret_cast<uint4*>(pk + 4);
        }
    }
}

// ---------------- Kernel 2: row & col histograms (int atomics) -------------
__global__ void hist_kernel(const int* __restrict__ ei, int* __restrict__ cnt_row,
                            int* __restrict__ cnt_col, int E) {
    int i = blockIdx.x * blockDim.x + threadIdx.x;
    int stride = gridDim.x * blockDim.x;
    for (; i < E; i += stride) {
        atomicAdd(&cnt_row[ei[i]], 1);
        atomicAdd(&cnt_col[ei[E + i]], 1);
    }
}

// ---------------- Kernel 3: blocksum + dinv + combo (fused) ----------------
__global__ void blocksum_kernel(const int* __restrict__ cnt_col, const int* __restrict__ cnt_row,
                                float* __restrict__ dinv, int* __restrict__ bsum,
                                const float* __restrict__ emb0, const float* __restrict__ emb1,
                                const float* __restrict__ emb2, float* __restrict__ combo, int n) {
    const int i = blockIdx.x * 256 + threadIdx.x;
    if (i < n) {
        int d = cnt_row[i];
        dinv[i] = (d > 0) ? rsqrtf((float)d) : 0.0f;
    }
    int v = (i < n) ? cnt_col[i] : 0;
    #pragma unroll
    for (int d = 32; d; d >>= 1) v += __shfl_down(v, d);
    __shared__ int wsum[4];
    if ((threadIdx.x & 63) == 0) wsum[threadIdx.x >> 6] = v;
    __syncthreads();
    if (threadIdx.x == 0) bsum[blockIdx.x] = wsum[0] + wsum[1] + wsum[2] + wsum[3];
    // combo table: blocks 0..59 compute one combo row each
    if (blockIdx.x < 60 && threadIdx.x < CC) {
        const int c = blockIdx.x, t = threadIdx.x;
        const int i0 = c / 12, j0 = (c % 12) / 2, k0 = c % 2;
        combo[c * CC + t] = emb0[i0 * CC + t] + emb1[j0 * CC + t] + emb2[k0 * CC + t];
    }
}

// ---------------- Kernels 4b/4c: scan of block sums, then offsets ----------
__global__ void bscan_kernel(const int* __restrict__ bsum, int* __restrict__ boff,
                             int nb, int* __restrict__ offs, int n) {
    __shared__ int tmp[256];
    const int t = threadIdx.x;
    int v = (t < nb) ? bsum[t] : 0;
    tmp[t] = v; __syncthreads();
    for (int d = 1; d < 256; d <<= 1) {
        int u = (t >= d) ? tmp[t - d] : 0; __syncthreads();
        tmp[t] += u; __syncthreads();
    }
    if (t < nb) boff[t] = tmp[t] - v;
    if (t == 255) offs[n] = tmp[255];     // total = E
}

__global__ void offs_kernel(const int* __restrict__ cnt, const int* __restrict__ boff,
                            int* __restrict__ offs, int* __restrict__ next, int n) {
    __shared__ int tmp[256];
    const int t = threadIdx.x;
    const int i = blockIdx.x * 256 + t;
    int v = (i < n) ? cnt[i] : 0;
    tmp[t] = v; __syncthreads();
    for (int d = 1; d < 256; d <<= 1) {
        int u = (t >= d) ? tmp[t - d] : 0; __syncthreads();
        tmp[t] += u; __syncthreads();
    }
    if (i < n) {
        int e = boff[blockIdx.x] + tmp[t] - v;
        offs[i] = e;
        next[i] = e;
    }
}

// ---------------- Kernel 5: fill CSR records (row|code packed, dinv_row) ---
// relies on n <= 65536 so row fits in 16 bits (n = 50000 here).
__global__ void fill_kernel(const int* __restrict__ ei, const int* __restrict__ ef,
                            const float* __restrict__ dinv, int* __restrict__ next,
                            int2* __restrict__ sc, int E) {
    int i = blockIdx.x * blockDim.x + threadIdx.x;
    int stride = gridDim.x * blockDim.x;
    for (; i < E; i += stride) {
        int r = ei[i];
        int c = ei[E + i];
        int pos = atomicAdd(&next[c], 1);
        int code = ef[i * 3 + 0] * 12 + ef[i * 3 + 1] * 2 + ef[i * 3 + 2];
        sc[pos] = make_int2(r | (code << 16), __float_as_int(dinv[r]));
    }
}

// ---------------- Kernel 7: gather (one 64-lane wave per node, unroll 4) ---
__global__ void gather_kernel(const ushort_t* __restrict__ xwb, const int2* __restrict__ sc,
                              const int* __restrict__ offs, const float* __restrict__ dinv,
                              const float* __restrict__ combo, float* __restrict__ out, int n) {
    const int v = blockIdx.x * 4 + (threadIdx.x >> 6);
    if (v >= n) return;
    const int lane = threadIdx.x & 63;
    int j = offs[v];
    const int end = offs[v + 1];
    float2 a0 = {0.f, 0.f}, a1 = {0.f, 0.f}, a2 = {0.f, 0.f}, a3 = {0.f, 0.f};

    #define GBODY(ACC, EDG)                                                              \
        {                                                                                \
            const int   r_ = (EDG).x & 0xFFFF, c_ = (EDG).x >> 16;                       \
            const float w_ = __int_as_float((EDG).y);                                    \
            const uint_t u_ = *reinterpret_cast<const uint_t*>(                          \
                &xwb[(size_t)r_ * CC + lane * 2]);                                       \
            const float2 k_ = *reinterpret_cast<const float2*>(&combo[c_ * CC + lane * 2]); \
            ACC.x += w_ * (__uint_as_float(u_ << 16) + k_.x);                            \
            ACC.y += w_ * (__uint_as_float(u_ & 0xFFFF0000u) + k_.y);                    \
        }

    for (; j + 4 <= end; j += 4) {
        const int2 e0 = sc[j], e1 = sc[j + 1], e2 = sc[j + 2], e3 = sc[j + 3];
        GBODY(a0, e0) GBODY(a1, e1) GBODY(a2, e2) GBODY(a3, e3)
    }
    for (; j < end; ++j) {
        const int2 e0 = sc[j];
        GBODY(a0, e0)
    }
    #undef GBODY

    const float s = dinv[v];
    *reinterpret_cast<float2*>(&out[(size_t)v * CC + lane * 2]) =
        make_float2(s * (a0.x + a1.x + a2.x + a3.x),
                    s * (a0.y + a1.y + a2.y + a3.y));
}

extern "C" void kernel_launch(void* const* d_in, const int* in_sizes, int n_in,
                              void* d_out, int out_size, void* d_ws, size_t ws_size,
                              hipStream_t stream) {
    const float* x      = (const float*)d_in[0];
    const int*   ei     = (const int*)d_in[1];
    const int*   ef     = (const int*)d_in[2];
    const float* weight = (const float*)d_in[3];
    const float* emb0   = (const float*)d_in[4];
    const float* emb1   = (const float*)d_in[5];
    const float* emb2   = (const float*)d_in[6];
    float* out = (float*)d_out;

    const int n = in_sizes[0] / CC;        // 50000
    const int E = in_sizes[1] / 2;         // 625000
    const int nb = (n + 255) / 256;        // 196

    // ---- workspace layout (16B-aligned chunks) ----
    char* p = (char*)d_ws;
    auto alloc = [&](size_t bytes) {
        char* r = p;
        p += (bytes + 15) & ~(size_t)15;
        return r;
    };
    ushort_t* xwb   = (ushort_t*)alloc((size_t)n * CC * sizeof(ushort_t));
    float* combo    = (float*)alloc(60 * CC * sizeof(float));
    float* dinv     = (float*)alloc(n * sizeof(float));
    int*   cnt_row  = (int*)alloc(n * sizeof(int));
    int*   cnt_col  = (int*)alloc(n * sizeof(int));
    int*   offs     = (int*)alloc((n + 1) * sizeof(int));
    int*   next     = (int*)alloc(n * sizeof(int));
    int*   bsum     = (int*)alloc(nb * sizeof(int));
    int*   boff     = (int*)alloc(nb * sizeof(int));
    int2*  sc       = (int2*)alloc((size_t)E * sizeof(int2));

    hipMemsetAsync(cnt_row, 0, n * sizeof(int), stream);
    hipMemsetAsync(cnt_col, 0, n * sizeof(int), stream);

    // 1) xw = x @ W (bf16 output)
    xw_kernel<<<(n + 127) / 128, 256, 0, stream>>>(x, weight, xwb, n);
    // 2) histograms
    hist_kernel<<<2048, 256, 0, stream>>>(ei, cnt_row, cnt_col, E);
    // 3) blocksum + dinv + combo
    blocksum_kernel<<<nb, 256, 0, stream>>>(cnt_col, cnt_row, dinv, bsum,
                                            emb0, emb1, emb2, combo, n);
    // 4) scan
    bscan_kernel<<<1, 256, 0, stream>>>(bsum, boff, nb, offs, n);
    offs_kernel<<<nb, 256, 0, stream>>>(cnt_col, boff, offs, next, n);
    // 5) fill CSR records
    fill_kernel<<<2048, 256, 0, stream>>>(ei, ef, dinv, next, sc, E);
    // 6) gather
    gather_kernel<<<(n + 3) / 4, 256, 0, stream>>>(xwb, sc, offs, dinv, combo, out, n);
}